// Round 1
// baseline (889.916 us; speedup 1.0000x reference)
//
#include <hip/hip_runtime.h>
#include <hip/hip_bf16.h>
#include <math.h>

#define N_PTS  100000
#define M_CL   2048
#define E_EDG  65536
#define IN_DIM 512
#define HID    256
// TAU = 0.5  -> 1/TAU = 2.0 ;  LAMDA = 1.0 (folded)

// ---------------- workspace layout (bytes) ----------------
// zero-region (memset each call):
static const size_t OFF_POSACC = 0;              // M floats
static const size_t OFF_NEGSUM = 8192;           // M floats
static const size_t OFF_HISTP  = 16384;          // M ints
static const size_t OFF_CURP   = 24576;          // M ints
static const size_t OFF_HISTE  = 32768;          // M ints
static const size_t OFF_CURE   = 40960;          // M ints
static const size_t OFF_LOSS   = 49152;          // 1 double
static const size_t ZERO_BYTES = 49408;
// non-zeroed scratch:
static const size_t OFF_STARTP = 49664;          // M+1 ints (pad)
static const size_t OFF_STARTE = 58112;          // M+1 ints (pad)
static const size_t OFF_SORTPT = 66560;          // N ints (pad to 400128)
static const size_t OFF_SCOL   = 466688;         // E ints
static const size_t OFF_SVAL   = 728832;         // E floats
static const size_t OFF_CNT    = 990976;         // M floats
static const size_t OFF_XC     = 999168;         // M*512 floats = 4 MB
static const size_t OFF_HC     = 5193472;        // M*256 floats
static const size_t OFF_T0     = 7290624;        // M*256 floats
static const size_t OFF_Q      = 9387776;        // M*256 floats
static const size_t OFF_HN     = 11484928;       // M*256 floats
static const size_t OFF_NEG    = 13582080;       // M*M floats = 16 MB
// total ~30.4 MB

// ---------------- CSR build ----------------
__global__ __launch_bounds__(256) void k_hist(const int* __restrict__ idx, int n, int* __restrict__ hist){
  int i = blockIdx.x*256 + threadIdx.x;
  if (i < n) atomicAdd(&hist[idx[i]], 1);
}

__global__ __launch_bounds__(256) void k_scan(const int* __restrict__ hist, int* __restrict__ start){
  __shared__ int part[256];
  int t = threadIdx.x;
  int v[8]; int s = 0;
#pragma unroll
  for (int j=0;j<8;j++){ v[j] = hist[t*8+j]; s += v[j]; }
  part[t] = s;
  __syncthreads();
  if (t == 0){
    int run = 0;
    for (int i=0;i<256;i++){ int tmp = part[i]; part[i] = run; run += tmp; }
  }
  __syncthreads();
  int run = part[t];
#pragma unroll
  for (int j=0;j<8;j++){ start[t*8+j] = run; run += v[j]; }
  if (t == 255) start[M_CL] = run;
}

__global__ __launch_bounds__(256) void k_scatter_pts(const int* __restrict__ assign, const int* __restrict__ start,
                                                     int* __restrict__ cur, int* __restrict__ out){
  int i = blockIdx.x*256 + threadIdx.x;
  if (i < N_PTS){
    int r = assign[i];
    int p = start[r] + atomicAdd(&cur[r], 1);
    out[p] = i;
  }
}

__global__ __launch_bounds__(256) void k_scatter_edges(const int* __restrict__ rows, const int* __restrict__ cols,
                                                       const float* __restrict__ vals, const int* __restrict__ start,
                                                       int* __restrict__ cur, int* __restrict__ scol,
                                                       float* __restrict__ sval){
  int e = blockIdx.x*256 + threadIdx.x;
  if (e < E_EDG){
    int r = rows[e];
    int p = start[r] + atomicAdd(&cur[r], 1);
    scol[p] = cols[e];
    sval[p] = vals[e];
  }
}

// ---------------- Xc = segsum(p * x), cnt = segsum(p) ----------------
__global__ __launch_bounds__(256) void k_cluster_agg(const float* __restrict__ x, const float* __restrict__ pv,
                                                     const int* __restrict__ sorted_pt, const int* __restrict__ start,
                                                     float* __restrict__ Xc, float* __restrict__ cnt){
  int m = blockIdx.x, t = threadIdx.x;
  int s0 = start[m], s1 = start[m+1];
  float a0 = 0.f, a1 = 0.f, c = 0.f;
  for (int p=s0;p<s1;p++){
    int row = sorted_pt[p];
    float w = pv[row];
    float2 xv = *reinterpret_cast<const float2*>(x + (size_t)row*IN_DIM + t*2);
    a0 = fmaf(w, xv.x, a0);
    a1 = fmaf(w, xv.y, a1);
    c += w;
  }
  *reinterpret_cast<float2*>(Xc + (size_t)m*IN_DIM + t*2) = make_float2(a0, a1);
  if (t == 0) cnt[m] = c;
}

// ---------------- small GEMM: out[r][c] = sum_k A[r][k] W[k][c] + scale_r * bias[c] ----------------
template<int K, bool RELU, bool SCALED>
__global__ __launch_bounds__(256) void k_gemm_small(const float* __restrict__ A, const float* __restrict__ W,
                                                    const float* __restrict__ bias, const float* __restrict__ scale,
                                                    float* __restrict__ out){
  __shared__ __align__(16) float a_sh[4][K];
  int rb = blockIdx.x*4, t = threadIdx.x;
  for (int i=t; i<K; i+=256){
    int r = i/(K/4), k4 = i%(K/4);
    reinterpret_cast<float4*>(a_sh[r])[k4] = reinterpret_cast<const float4*>(A + (size_t)(rb+r)*K)[k4];
  }
  __syncthreads();
  float acc[4] = {0.f,0.f,0.f,0.f};
#pragma unroll 2
  for (int k=0;k<K;k+=4){
    float w0 = W[(size_t)(k+0)*HID + t];
    float w1 = W[(size_t)(k+1)*HID + t];
    float w2 = W[(size_t)(k+2)*HID + t];
    float w3 = W[(size_t)(k+3)*HID + t];
#pragma unroll
    for (int r=0;r<4;r++){
      float4 av = *reinterpret_cast<const float4*>(&a_sh[r][k]);
      acc[r] = fmaf(av.x, w0, acc[r]);
      acc[r] = fmaf(av.y, w1, acc[r]);
      acc[r] = fmaf(av.z, w2, acc[r]);
      acc[r] = fmaf(av.w, w3, acc[r]);
    }
  }
  float b = bias[t];
#pragma unroll
  for (int r=0;r<4;r++){
    float s = SCALED ? scale[rb+r] : 1.0f;
    float v = acc[r] + s*b;
    if (RELU) v = fmaxf(v, 0.0f);
    out[(size_t)(rb+r)*HID + t] = v;
  }
}

// ---------------- row L2-normalize (F.normalize semantics) ----------------
__global__ __launch_bounds__(256) void k_norm_rows(const float* __restrict__ in, float* __restrict__ out){
  int r = blockIdx.x, t = threadIdx.x;
  float v = in[(size_t)r*HID + t];
  float ss = v*v;
#pragma unroll
  for (int off=32;off;off>>=1) ss += __shfl_xor(ss, off, 64);
  __shared__ float wsum[4];
  if ((t&63) == 0) wsum[t>>6] = ss;
  __syncthreads();
  float tot = wsum[0]+wsum[1]+wsum[2]+wsum[3];
  float inv = 1.0f / fmaxf(sqrtf(tot), 1e-12f);
  out[(size_t)r*HID + t] = v*inv;
}

// ---------------- fused target encoder + pos_sim accumulation ----------------
// 64 rows/block, 256 threads, 8x8 micro-tiles. Phase1: t = x@Wt0+bt0 (K=512, KT=32 LDS tiles).
// t round-trips LDS transposed [256][64]. Phase2: v = t@Wt1+bt1 (Wt1 streamed, L1-hot).
// Epilogue: rownorm (shfl over the 32 col-threads), dot with q[assign], atomicAdd posacc.
__global__ __launch_bounds__(256) void k_target(const float* __restrict__ x,
    const float* __restrict__ Wt0, const float* __restrict__ bt0,
    const float* __restrict__ Wt1, const float* __restrict__ bt1,
    const float* __restrict__ q, const int* __restrict__ assign,
    const float* __restrict__ pv, float* __restrict__ posacc){
  __shared__ __align__(16) float smem[16384];   // 64 KB
  float* xs  = smem;          // [32][64]
  float* ws1 = smem + 2048;   // [32][256]
  float* tt  = smem;          // [256][64]  (phase 2, aliases phase-1 buffers)

  const int t  = threadIdx.x;
  const int tr = t >> 5;      // 0..7  -> rows tr*8 .. tr*8+7
  const int tc = t & 31;      // 0..31 -> cols tc*8 .. tc*8+7
  const int r0 = blockIdx.x * 64;

  float acc[8][8];
#pragma unroll
  for (int i=0;i<8;i++)
#pragma unroll
    for (int j=0;j<8;j++) acc[i][j] = 0.f;

  const int lrow = t & 63;
  const int lch  = t >> 6;    // 0..3
  const int grow_s = r0 + lrow;
  const bool rv = grow_s < N_PTS;

  for (int k0=0;k0<IN_DIM;k0+=32){
    float4 xv0 = make_float4(0,0,0,0), xv1 = make_float4(0,0,0,0);
    if (rv){
      const float* xp = x + (size_t)grow_s*IN_DIM + k0 + lch*8;
      xv0 = reinterpret_cast<const float4*>(xp)[0];
      xv1 = reinterpret_cast<const float4*>(xp)[1];
    }
    float4 wv[8];
#pragma unroll
    for (int j=0;j<8;j++){
      int kk = lch*8 + j;
      wv[j] = *reinterpret_cast<const float4*>(Wt0 + (size_t)(k0+kk)*HID + lrow*4);
    }
    __syncthreads();           // previous tile fully consumed
    {
      int kb = lch*8;
      xs[(kb+0)*64 + lrow] = xv0.x; xs[(kb+1)*64 + lrow] = xv0.y;
      xs[(kb+2)*64 + lrow] = xv0.z; xs[(kb+3)*64 + lrow] = xv0.w;
      xs[(kb+4)*64 + lrow] = xv1.x; xs[(kb+5)*64 + lrow] = xv1.y;
      xs[(kb+6)*64 + lrow] = xv1.z; xs[(kb+7)*64 + lrow] = xv1.w;
#pragma unroll
      for (int j=0;j<8;j++)
        *reinterpret_cast<float4*>(ws1 + (size_t)(lch*8+j)*HID + lrow*4) = wv[j];
    }
    __syncthreads();
#pragma unroll 4
    for (int kk=0;kk<32;kk++){
      float4 a0 = *reinterpret_cast<const float4*>(&xs[kk*64 + tr*8]);
      float4 a1 = *reinterpret_cast<const float4*>(&xs[kk*64 + tr*8 + 4]);
      float4 w0 = *reinterpret_cast<const float4*>(&ws1[kk*HID + tc*8]);
      float4 w1 = *reinterpret_cast<const float4*>(&ws1[kk*HID + tc*8 + 4]);
      float a[8] = {a0.x,a0.y,a0.z,a0.w,a1.x,a1.y,a1.z,a1.w};
      float w[8] = {w0.x,w0.y,w0.z,w0.w,w1.x,w1.y,w1.z,w1.w};
#pragma unroll
      for (int i=0;i<8;i++)
#pragma unroll
        for (int j=0;j<8;j++) acc[i][j] = fmaf(a[i], w[j], acc[i][j]);
    }
  }

  __syncthreads();             // all phase-1 LDS reads done; smem becomes tt
  {
    float bt0v[8];
    *reinterpret_cast<float4*>(bt0v)   = *reinterpret_cast<const float4*>(bt0 + tc*8);
    *reinterpret_cast<float4*>(bt0v+4) = *reinterpret_cast<const float4*>(bt0 + tc*8 + 4);
#pragma unroll
    for (int j=0;j<8;j++){
      int c = tc*8 + j;
      float4 lo = make_float4(acc[0][j]+bt0v[j], acc[1][j]+bt0v[j], acc[2][j]+bt0v[j], acc[3][j]+bt0v[j]);
      float4 hi = make_float4(acc[4][j]+bt0v[j], acc[5][j]+bt0v[j], acc[6][j]+bt0v[j], acc[7][j]+bt0v[j]);
      *reinterpret_cast<float4*>(&tt[c*64 + tr*8])     = lo;
      *reinterpret_cast<float4*>(&tt[c*64 + tr*8 + 4]) = hi;
    }
  }
  __syncthreads();

#pragma unroll
  for (int i=0;i<8;i++)
#pragma unroll
    for (int j=0;j<8;j++) acc[i][j] = 0.f;

  float4 w2a = *reinterpret_cast<const float4*>(Wt1 + tc*8);
  float4 w2b = *reinterpret_cast<const float4*>(Wt1 + tc*8 + 4);
#pragma unroll 4
  for (int kk=0;kk<HID;kk++){
    float4 cw0 = w2a, cw1 = w2b;
    if (kk+1 < HID){
      w2a = *reinterpret_cast<const float4*>(Wt1 + (size_t)(kk+1)*HID + tc*8);
      w2b = *reinterpret_cast<const float4*>(Wt1 + (size_t)(kk+1)*HID + tc*8 + 4);
    }
    float4 a0 = *reinterpret_cast<const float4*>(&tt[kk*64 + tr*8]);
    float4 a1 = *reinterpret_cast<const float4*>(&tt[kk*64 + tr*8 + 4]);
    float a[8] = {a0.x,a0.y,a0.z,a0.w,a1.x,a1.y,a1.z,a1.w};
    float w[8] = {cw0.x,cw0.y,cw0.z,cw0.w,cw1.x,cw1.y,cw1.z,cw1.w};
#pragma unroll
    for (int i=0;i<8;i++)
#pragma unroll
      for (int j=0;j<8;j++) acc[i][j] = fmaf(a[i], w[j], acc[i][j]);
  }

  // epilogue: +bt1, row L2-norm, dot with q[assign], scatter to posacc
  {
    float bt1v[8];
    *reinterpret_cast<float4*>(bt1v)   = *reinterpret_cast<const float4*>(bt1 + tc*8);
    *reinterpret_cast<float4*>(bt1v+4) = *reinterpret_cast<const float4*>(bt1 + tc*8 + 4);
#pragma unroll
    for (int i=0;i<8;i++)
#pragma unroll
      for (int j=0;j<8;j++) acc[i][j] += bt1v[j];
  }
#pragma unroll
  for (int i=0;i<8;i++){
    int grow = r0 + tr*8 + i;
    bool ok = grow < N_PTS;
    int cl = ok ? assign[grow] : 0;
    float pw = ok ? pv[grow] : 0.f;

    float ss = 0.f;
#pragma unroll
    for (int j=0;j<8;j++) ss = fmaf(acc[i][j], acc[i][j], ss);
#pragma unroll
    for (int off=16;off;off>>=1) ss += __shfl_xor(ss, off, 32);
    float inv = 1.0f / fmaxf(sqrtf(ss), 1e-12f);

    const float* qp = q + (size_t)cl*HID + tc*8;
    float4 q0 = *reinterpret_cast<const float4*>(qp);
    float4 q1 = *reinterpret_cast<const float4*>(qp + 4);
    float qv[8] = {q0.x,q0.y,q0.z,q0.w,q1.x,q1.y,q1.z,q1.w};
    float d = 0.f;
#pragma unroll
    for (int j=0;j<8;j++) d = fmaf(acc[i][j], qv[j], d);
#pragma unroll
    for (int off=16;off;off>>=1) d += __shfl_xor(d, off, 32);

    if (tc == 0 && ok)
      atomicAdd(&posacc[cl], pw * d * inv * 2.0f);   // * (1/TAU)
  }
}

// ---------------- neg = exp(hn @ hn^T / TAU), negsum = rowsum ----------------
__global__ __launch_bounds__(256) void k_neg(const float* __restrict__ hn, float* __restrict__ neg,
                                             float* __restrict__ negsum){
  __shared__ __align__(16) float at[64*64];
  __shared__ __align__(16) float bt[64*64];
  const int t  = threadIdx.x;
  const int ty = t >> 4, tx = t & 15;
  const int i0 = blockIdx.y*64, j0 = blockIdx.x*64;
  const int r  = t & 63, kq = t >> 6;
  float acc[4][4] = {};
  for (int kc=0;kc<4;kc++){
    int k0 = kc*64;
    float4 av[4], bv[4];
#pragma unroll
    for (int j=0;j<4;j++){
      int kb = kq*16 + j*4;
      av[j] = *reinterpret_cast<const float4*>(hn + (size_t)(i0+r)*HID + k0 + kb);
      bv[j] = *reinterpret_cast<const float4*>(hn + (size_t)(j0+r)*HID + k0 + kb);
    }
    __syncthreads();
#pragma unroll
    for (int j=0;j<4;j++){
      int kb = kq*16 + j*4;
      at[(kb+0)*64+r]=av[j].x; at[(kb+1)*64+r]=av[j].y; at[(kb+2)*64+r]=av[j].z; at[(kb+3)*64+r]=av[j].w;
      bt[(kb+0)*64+r]=bv[j].x; bt[(kb+1)*64+r]=bv[j].y; bt[(kb+2)*64+r]=bv[j].z; bt[(kb+3)*64+r]=bv[j].w;
    }
    __syncthreads();
#pragma unroll 8
    for (int k=0;k<64;k++){
      float4 a = *reinterpret_cast<const float4*>(&at[k*64 + ty*4]);
      float4 b = *reinterpret_cast<const float4*>(&bt[k*64 + tx*4]);
      float aa[4] = {a.x,a.y,a.z,a.w}, bb[4] = {b.x,b.y,b.z,b.w};
#pragma unroll
      for (int ii=0;ii<4;ii++)
#pragma unroll
        for (int jj=0;jj<4;jj++) acc[ii][jj] = fmaf(aa[ii], bb[jj], acc[ii][jj]);
    }
  }
#pragma unroll
  for (int ii=0;ii<4;ii++){
    float4 e;
    e.x = __expf(acc[ii][0]*2.0f);
    e.y = __expf(acc[ii][1]*2.0f);
    e.z = __expf(acc[ii][2]*2.0f);
    e.w = __expf(acc[ii][3]*2.0f);
    int row = i0 + ty*4 + ii;
    *reinterpret_cast<float4*>(neg + (size_t)row*M_CL + j0 + tx*4) = e;
    float rs = e.x+e.y+e.z+e.w;
#pragma unroll
    for (int off=8;off;off>>=1) rs += __shfl_xor(rs, off, 16);
    if (tx == 0) atomicAdd(&negsum[row], rs);
  }
}

// ---------------- loss: per row i, gather partition row + both log terms ----------------
__global__ __launch_bounds__(256) void k_loss(const float* __restrict__ neg, const float* __restrict__ negsum,
                                              const float* __restrict__ posacc, const int* __restrict__ start,
                                              const int* __restrict__ scol, const float* __restrict__ sval,
                                              double* __restrict__ loss){
  const int i = blockIdx.x, t = threadIdx.x;
  float ps[8] = {};
  const int s0 = start[i], s1 = start[i+1];
  for (int e=s0;e<s1;e++){
    int c = scol[e];
    float v = sval[e];
    const float* row = neg + (size_t)c*M_CL + t;
#pragma unroll
    for (int jj=0;jj<8;jj++) ps[jj] = fmaf(v, row[jj*256], ps[jj]);
  }
  float pos = __expf(posacc[i]);
  float part = 0.f;
#pragma unroll
  for (int jj=0;jj<8;jj++){
    int j = t + jj*256;
    part += __logf(pos + negsum[j]) - __logf(pos + ps[jj]);  // LAMDA = 1
  }
#pragma unroll
  for (int off=32;off;off>>=1) part += __shfl_xor(part, off, 64);
  __shared__ float wsum[4];
  if ((t&63) == 0) wsum[t>>6] = part;
  __syncthreads();
  if (t == 0){
    double s = (double)wsum[0] + (double)wsum[1] + (double)wsum[2] + (double)wsum[3];
    atomicAdd(loss, s);
  }
}

__global__ void k_finalize(const double* __restrict__ loss, float* __restrict__ out){
  if (threadIdx.x == 0 && blockIdx.x == 0)
    out[0] = (float)(loss[0] / ((double)M_CL * (double)M_CL));
}

// ---------------- launch ----------------
extern "C" void kernel_launch(void* const* d_in, const int* in_sizes, int n_in,
                              void* d_out, int out_size, void* d_ws, size_t ws_size,
                              hipStream_t stream){
  const float* x    = (const float*)d_in[0];
  const float* We0  = (const float*)d_in[1];
  const float* be0  = (const float*)d_in[2];
  const float* We1  = (const float*)d_in[3];
  const float* be1  = (const float*)d_in[4];
  const float* Wt0  = (const float*)d_in[5];
  const float* bt0  = (const float*)d_in[6];
  const float* Wt1  = (const float*)d_in[7];
  const float* bt1  = (const float*)d_in[8];
  const float* Wp0  = (const float*)d_in[9];
  const float* bp0  = (const float*)d_in[10];
  const float* Wp1  = (const float*)d_in[11];
  const float* bp1  = (const float*)d_in[12];
  const float* pv   = (const float*)d_in[13];
  const float* cgv  = (const float*)d_in[14];
  const int*   pas  = (const int*)d_in[15];
  const int*   cgr  = (const int*)d_in[16];
  const int*   cgc  = (const int*)d_in[17];
  // d_in[18] = neg_idx: unused by the reference.

  char* ws = (char*)d_ws;
  float*  posacc  = (float*)(ws + OFF_POSACC);
  float*  negsum  = (float*)(ws + OFF_NEGSUM);
  int*    hist_p  = (int*)  (ws + OFF_HISTP);
  int*    cur_p   = (int*)  (ws + OFF_CURP);
  int*    hist_e  = (int*)  (ws + OFF_HISTE);
  int*    cur_e   = (int*)  (ws + OFF_CURE);
  double* lossd   = (double*)(ws + OFF_LOSS);
  int*    start_p = (int*)  (ws + OFF_STARTP);
  int*    start_e = (int*)  (ws + OFF_STARTE);
  int*    sortpt  = (int*)  (ws + OFF_SORTPT);
  int*    scol    = (int*)  (ws + OFF_SCOL);
  float*  sval    = (float*)(ws + OFF_SVAL);
  float*  cnt     = (float*)(ws + OFF_CNT);
  float*  Xc      = (float*)(ws + OFF_XC);
  float*  hc      = (float*)(ws + OFF_HC);
  float*  t0      = (float*)(ws + OFF_T0);
  float*  qb      = (float*)(ws + OFF_Q);
  float*  hn      = (float*)(ws + OFF_HN);
  float*  negbuf  = (float*)(ws + OFF_NEG);

  hipMemsetAsync(ws, 0, ZERO_BYTES, stream);

  k_hist<<<(N_PTS+255)/256, 256, 0, stream>>>(pas, N_PTS, hist_p);
  k_hist<<<(E_EDG+255)/256, 256, 0, stream>>>(cgr, E_EDG, hist_e);
  k_scan<<<1, 256, 0, stream>>>(hist_p, start_p);
  k_scan<<<1, 256, 0, stream>>>(hist_e, start_e);
  k_scatter_pts<<<(N_PTS+255)/256, 256, 0, stream>>>(pas, start_p, cur_p, sortpt);
  k_scatter_edges<<<(E_EDG+255)/256, 256, 0, stream>>>(cgr, cgc, cgv, start_e, cur_e, scol, sval);

  k_cluster_agg<<<M_CL, 256, 0, stream>>>(x, pv, sortpt, start_p, Xc, cnt);

  k_gemm_small<512,false,true ><<<M_CL/4, 256, 0, stream>>>(Xc, We0, be0, cnt, t0);   // hc_pre
  k_gemm_small<256,false,true ><<<M_CL/4, 256, 0, stream>>>(t0, We1, be1, cnt, hc);   // hc
  k_gemm_small<256,true ,false><<<M_CL/4, 256, 0, stream>>>(hc, Wp0, bp0, nullptr, t0); // relu(hc@Wp0+bp0)
  k_gemm_small<256,false,false><<<M_CL/4, 256, 0, stream>>>(t0, Wp1, bp1, nullptr, qb); // q_pre

  k_norm_rows<<<M_CL, 256, 0, stream>>>(qb, qb);  // q
  k_norm_rows<<<M_CL, 256, 0, stream>>>(hc, hn);  // hn

  k_target<<<(N_PTS+63)/64, 256, 0, stream>>>(x, Wt0, bt0, Wt1, bt1, qb, pas, pv, posacc);

  dim3 g2(M_CL/64, M_CL/64);
  k_neg<<<g2, 256, 0, stream>>>(hn, negbuf, negsum);

  k_loss<<<M_CL, 256, 0, stream>>>(negbuf, negsum, posacc, start_e, scol, sval, lossd);
  k_finalize<<<1, 64, 0, stream>>>(lossd, (float*)d_out);
}

// Round 2
// 461.625 us; speedup vs baseline: 1.9278x; 1.9278x over previous
//
#include <hip/hip_runtime.h>
#include <hip/hip_bf16.h>
#include <math.h>

#define N_PTS  100000
#define M_CL   2048
#define E_EDG  65536
#define IN_DIM 512
#define HID    256
// TAU = 0.5 -> 1/TAU = 2.0 ; LAMDA = 1.0 (folded)

typedef unsigned short u16;
typedef __attribute__((ext_vector_type(8))) short bf16x8;
typedef __attribute__((ext_vector_type(4))) float f32x4;

__device__ __forceinline__ u16 f2bf(float f){
  __hip_bfloat16 h = __float2bfloat16(f);
  return *reinterpret_cast<u16*>(&h);
}

// ---------------- workspace layout (bytes) ----------------
static const size_t OFF_POSACC = 0;              // M floats
static const size_t OFF_NEGSUM = 8192;           // M floats
static const size_t OFF_HISTP  = 16384;          // M ints
static const size_t OFF_CURP   = 24576;          // M ints
static const size_t OFF_HISTE  = 32768;          // M ints
static const size_t OFF_CURE   = 40960;          // M ints
static const size_t OFF_LOSS   = 49152;          // 1 double
static const size_t ZERO_BYTES = 49408;
static const size_t OFF_STARTP = 49664;          // M+1 ints
static const size_t OFF_STARTE = 58112;          // M+1 ints
static const size_t OFF_SORTPT = 66560;          // N ints
static const size_t OFF_SCOL   = 466688;         // E ints
static const size_t OFF_SVAL   = 728832;         // E floats
static const size_t OFF_CNT    = 990976;         // M floats
static const size_t OFF_XC     = 999168;         // M*512 floats
static const size_t OFF_HC     = 5193472;        // M*256 floats
static const size_t OFF_T0     = 7290624;        // M*256 floats
static const size_t OFF_Q      = 9387776;        // M*256 floats
static const size_t OFF_HN     = 11484928;       // M*256 floats
static const size_t OFF_NEG    = 13582080;       // M*M floats = 16 MB
// Wt0t/Wt1t alias the NEG region: consumed by k_target_mfma, which completes
// before k_neg writes negbuf (stream-ordered).
static const size_t OFF_WT0T   = OFF_NEG;               // 256*512 bf16 = 256 KB
static const size_t OFF_WT1T   = OFF_NEG + 262144;      // 256*256 bf16 = 128 KB

// ---------------- CSR build ----------------
__global__ __launch_bounds__(256) void k_hist(const int* __restrict__ idx, int n, int* __restrict__ hist){
  int i = blockIdx.x*256 + threadIdx.x;
  if (i < n) atomicAdd(&hist[idx[i]], 1);
}

__global__ __launch_bounds__(256) void k_scan(const int* __restrict__ hist, int* __restrict__ start){
  __shared__ int part[256];
  int t = threadIdx.x;
  int v[8]; int s = 0;
#pragma unroll
  for (int j=0;j<8;j++){ v[j] = hist[t*8+j]; s += v[j]; }
  part[t] = s;
  __syncthreads();
  if (t == 0){
    int run = 0;
    for (int i=0;i<256;i++){ int tmp = part[i]; part[i] = run; run += tmp; }
  }
  __syncthreads();
  int run = part[t];
#pragma unroll
  for (int j=0;j<8;j++){ start[t*8+j] = run; run += v[j]; }
  if (t == 255) start[M_CL] = run;
}

__global__ __launch_bounds__(256) void k_scatter_pts(const int* __restrict__ assign, const int* __restrict__ start,
                                                     int* __restrict__ cur, int* __restrict__ out){
  int i = blockIdx.x*256 + threadIdx.x;
  if (i < N_PTS){
    int r = assign[i];
    int p = start[r] + atomicAdd(&cur[r], 1);
    out[p] = i;
  }
}

__global__ __launch_bounds__(256) void k_scatter_edges(const int* __restrict__ rows, const int* __restrict__ cols,
                                                       const float* __restrict__ vals, const int* __restrict__ start,
                                                       int* __restrict__ cur, int* __restrict__ scol,
                                                       float* __restrict__ sval){
  int e = blockIdx.x*256 + threadIdx.x;
  if (e < E_EDG){
    int r = rows[e];
    int p = start[r] + atomicAdd(&cur[r], 1);
    scol[p] = cols[e];
    sval[p] = vals[e];
  }
}

// ---------------- Xc = segsum(p * x), cnt = segsum(p) ----------------
__global__ __launch_bounds__(256) void k_cluster_agg(const float* __restrict__ x, const float* __restrict__ pv,
                                                     const int* __restrict__ sorted_pt, const int* __restrict__ start,
                                                     float* __restrict__ Xc, float* __restrict__ cnt){
  int m = blockIdx.x, t = threadIdx.x;
  int s0 = start[m], s1 = start[m+1];
  float a0 = 0.f, a1 = 0.f, c = 0.f;
  for (int p=s0;p<s1;p++){
    int row = sorted_pt[p];
    float w = pv[row];
    float2 xv = *reinterpret_cast<const float2*>(x + (size_t)row*IN_DIM + t*2);
    a0 = fmaf(w, xv.x, a0);
    a1 = fmaf(w, xv.y, a1);
    c += w;
  }
  *reinterpret_cast<float2*>(Xc + (size_t)m*IN_DIM + t*2) = make_float2(a0, a1);
  if (t == 0) cnt[m] = c;
}

// ---------------- small GEMM (M-scale chains) ----------------
template<int K, bool RELU, bool SCALED>
__global__ __launch_bounds__(256) void k_gemm_small(const float* __restrict__ A, const float* __restrict__ W,
                                                    const float* __restrict__ bias, const float* __restrict__ scale,
                                                    float* __restrict__ out){
  __shared__ __align__(16) float a_sh[4][K];
  int rb = blockIdx.x*4, t = threadIdx.x;
  for (int i=t; i<K; i+=256){
    int r = i/(K/4), k4 = i%(K/4);
    reinterpret_cast<float4*>(a_sh[r])[k4] = reinterpret_cast<const float4*>(A + (size_t)(rb+r)*K)[k4];
  }
  __syncthreads();
  float acc[4] = {0.f,0.f,0.f,0.f};
#pragma unroll 2
  for (int k=0;k<K;k+=4){
    float w0 = W[(size_t)(k+0)*HID + t];
    float w1 = W[(size_t)(k+1)*HID + t];
    float w2 = W[(size_t)(k+2)*HID + t];
    float w3 = W[(size_t)(k+3)*HID + t];
#pragma unroll
    for (int r=0;r<4;r++){
      float4 av = *reinterpret_cast<const float4*>(&a_sh[r][k]);
      acc[r] = fmaf(av.x, w0, acc[r]);
      acc[r] = fmaf(av.y, w1, acc[r]);
      acc[r] = fmaf(av.z, w2, acc[r]);
      acc[r] = fmaf(av.w, w3, acc[r]);
    }
  }
  float b = bias[t];
#pragma unroll
  for (int r=0;r<4;r++){
    float s = SCALED ? scale[rb+r] : 1.0f;
    float v = acc[r] + s*b;
    if (RELU) v = fmaxf(v, 0.0f);
    out[(size_t)(rb+r)*HID + t] = v;
  }
}

// ---------------- row L2-normalize ----------------
__global__ __launch_bounds__(256) void k_norm_rows(const float* __restrict__ in, float* __restrict__ out){
  int r = blockIdx.x, t = threadIdx.x;
  float v = in[(size_t)r*HID + t];
  float ss = v*v;
#pragma unroll
  for (int off=32;off;off>>=1) ss += __shfl_xor(ss, off, 64);
  __shared__ float wsum[4];
  if ((t&63) == 0) wsum[t>>6] = ss;
  __syncthreads();
  float tot = wsum[0]+wsum[1]+wsum[2]+wsum[3];
  float inv = 1.0f / fmaxf(sqrtf(tot), 1e-12f);
  out[(size_t)r*HID + t] = v*inv;
}

// ---------------- weight transpose+convert: W[k][n] f32 -> Wt[n][k] bf16 ----------------
template<int K>
__global__ __launch_bounds__(256) void k_transpose_bf16(const float* __restrict__ W, u16* __restrict__ Wt){
  int o = blockIdx.x*256 + threadIdx.x;   // o = n*K + k
  int n = o / K, k = o % K;
  Wt[o] = f2bf(W[(size_t)k*HID + n]);
}

// ---------------- fused target encoder (MFMA) + pos_sim accumulation ----------------
// Phase 1: tT[n][m] = sum_k Wt0t[n][k]*x[m][k] (A=Wt0t rows, B=x rows, f32->bf16 on the fly)
//   C-layout regs = 4 consecutive n at fixed m -> packed ds_write_b64 into swizzled t_lds[m][n].
// Phase 2: v[m][n] = sum_k t[m][k]*Wt1[k][n] (A=t_lds ds_read_b128, B=Wt1t rows).
//   v round-trips LDS as bf16 [n][m] (swizzled) for the row-wise epilogue.
// Epilogue: per row m: ||v||, dot(v, q[assign[m]]), atomicAdd posacc.
__global__ __launch_bounds__(256,3) void k_target_mfma(
    const float* __restrict__ x, const u16* __restrict__ Wt0t, const float* __restrict__ bt0,
    const u16* __restrict__ Wt1t, const float* __restrict__ bt1,
    const float* __restrict__ q, const int* __restrict__ assign,
    const float* __restrict__ pv, float* __restrict__ posacc){
  __shared__ u16 t_lds[64*256];       // 32 KB; phase-1 tT tile, then aliased as v tile
  __shared__ float red[2][4][64];
  const int t  = threadIdx.x;
  const int w  = t >> 6;     // wave: owns n in [w*64, w*64+64)
  const int l  = t & 63;
  const int lr = l & 15;     // frag lane-row
  const int lg = l >> 4;     // k-group
  const int r0 = blockIdx.x * 64;

  f32x4 acc[4][4];
#pragma unroll
  for (int i=0;i<4;i++)
#pragma unroll
    for (int j=0;j<4;j++){ acc[i][j].x=0.f; acc[i][j].y=0.f; acc[i][j].z=0.f; acc[i][j].w=0.f; }

  const float* xp[4];
#pragma unroll
  for (int mf=0;mf<4;mf++){
    int m = r0 + mf*16 + lr;
    if (m > N_PTS-1) m = N_PTS-1;          // tail clamp (masked in epilogue)
    xp[mf] = x + (size_t)m*IN_DIM + lg*8;
  }
  const u16* aB = Wt0t + (size_t)(w*64 + lr)*IN_DIM + lg*8;

  // ---- phase 1: K = 512
#pragma unroll 2
  for (int k0=0;k0<IN_DIM;k0+=32){
    bf16x8 bfr[4];
#pragma unroll
    for (int mf=0;mf<4;mf++){
      f32x4 lo = *reinterpret_cast<const f32x4*>(xp[mf] + k0);
      f32x4 hi = *reinterpret_cast<const f32x4*>(xp[mf] + k0 + 4);
      bf16x8 r;
      r[0]=(short)f2bf(lo.x); r[1]=(short)f2bf(lo.y); r[2]=(short)f2bf(lo.z); r[3]=(short)f2bf(lo.w);
      r[4]=(short)f2bf(hi.x); r[5]=(short)f2bf(hi.y); r[6]=(short)f2bf(hi.z); r[7]=(short)f2bf(hi.w);
      bfr[mf] = r;
    }
#pragma unroll
    for (int nf=0;nf<4;nf++){
      bf16x8 afr = *reinterpret_cast<const bf16x8*>(aB + (size_t)nf*16*IN_DIM + k0);
#pragma unroll
      for (int mf=0;mf<4;mf++)
        acc[nf][mf] = __builtin_amdgcn_mfma_f32_16x16x32_bf16(afr, bfr[mf], acc[nf][mf], 0,0,0);
    }
  }

  // ---- tT -> LDS (add bt0, bf16, swizzled 8B units: u = m*64 + (nq ^ ((m&7)<<1)))
#pragma unroll
  for (int nf=0;nf<4;nf++){
    int n0 = w*64 + nf*16 + lg*4;
    f32x4 bias = *reinterpret_cast<const f32x4*>(bt0 + n0);
    int nq = n0 >> 2;
#pragma unroll
    for (int mf=0;mf<4;mf++){
      int m = mf*16 + lr;
      f32x4 v = acc[nf][mf] + bias;
      uint2 p;
      p.x = (unsigned)f2bf(v.x) | ((unsigned)f2bf(v.y) << 16);
      p.y = (unsigned)f2bf(v.z) | ((unsigned)f2bf(v.w) << 16);
      int u = m*64 + (nq ^ ((m&7)<<1));
      *reinterpret_cast<uint2*>(&t_lds[u*4]) = p;
    }
  }
  __syncthreads();

  // ---- phase 2: K = 256
#pragma unroll
  for (int i=0;i<4;i++)
#pragma unroll
    for (int j=0;j<4;j++){ acc[i][j].x=0.f; acc[i][j].y=0.f; acc[i][j].z=0.f; acc[i][j].w=0.f; }
  const u16* bB = Wt1t + (size_t)(w*64 + lr)*HID + lg*8;
#pragma unroll 2
  for (int k0=0;k0<HID;k0+=32){
    int kq = (k0>>2) + lg*2;
    bf16x8 afr[4];
#pragma unroll
    for (int mf=0;mf<4;mf++){
      int m = mf*16 + lr;
      int u = m*64 + (kq ^ ((m&7)<<1));
      afr[mf] = *reinterpret_cast<const bf16x8*>(&t_lds[u*4]);
    }
#pragma unroll
    for (int nf=0;nf<4;nf++){
      bf16x8 bfr = *reinterpret_cast<const bf16x8*>(bB + (size_t)nf*16*HID + k0);
#pragma unroll
      for (int mf=0;mf<4;mf++)
        acc[mf][nf] = __builtin_amdgcn_mfma_f32_16x16x32_bf16(afr[mf], bfr, acc[mf][nf], 0,0,0);
    }
  }
  __syncthreads();   // all t_lds reads complete before overwrite

  // ---- v -> LDS as [n][m] bf16 (add bt1, swizzled: u = n*16 + ((m0>>2) ^ ((n&7)<<1)))
#pragma unroll
  for (int nf=0;nf<4;nf++){
    int n = w*64 + nf*16 + lr;
    float bias = bt1[n];
    int f = (n&7)<<1;
#pragma unroll
    for (int mf=0;mf<4;mf++){
      int m0 = mf*16 + lg*4;
      f32x4 v = acc[mf][nf];
      v.x += bias; v.y += bias; v.z += bias; v.w += bias;
      uint2 p;
      p.x = (unsigned)f2bf(v.x) | ((unsigned)f2bf(v.y) << 16);
      p.y = (unsigned)f2bf(v.z) | ((unsigned)f2bf(v.w) << 16);
      int u = n*16 + ((m0>>2) ^ f);
      *reinterpret_cast<uint2*>(&t_lds[u*4]) = p;
    }
  }
  __syncthreads();

  // ---- epilogue: 4 threads per row (n-chunks), then cross-wave combine
  {
    int m = t & 63, c = t >> 6;
    int gm = r0 + m;
    int cl = (gm < N_PTS) ? assign[gm] : 0;
    const float* qrow = q + (size_t)cl*HID + c*64;
    float ss = 0.f, d = 0.f;
#pragma unroll 4
    for (int i=0;i<64;i+=4){
      float qa[4];
      *reinterpret_cast<f32x4*>(qa) = *reinterpret_cast<const f32x4*>(qrow + i);
#pragma unroll
      for (int j=0;j<4;j++){
        int n = c*64 + i + j;
        int u = n*16 + ((m>>2) ^ ((n&7)<<1));
        float v = __uint_as_float((unsigned)t_lds[u*4 + (m&3)] << 16);
        ss = fmaf(v, v, ss);
        d  = fmaf(v, qa[j], d);
      }
    }
    red[0][c][m] = ss;
    red[1][c][m] = d;
  }
  __syncthreads();
  if (t < 64){
    int gm = r0 + t;
    if (gm < N_PTS){
      float ss = red[0][0][t]+red[0][1][t]+red[0][2][t]+red[0][3][t];
      float d  = red[1][0][t]+red[1][1][t]+red[1][2][t]+red[1][3][t];
      float inv = 1.0f / fmaxf(sqrtf(ss), 1e-12f);
      atomicAdd(&posacc[assign[gm]], pv[gm] * d * inv * 2.0f);   // * (1/TAU)
    }
  }
}

// ---------------- neg = exp(hn @ hn^T / TAU), negsum = rowsum ----------------
__global__ __launch_bounds__(256) void k_neg(const float* __restrict__ hn, float* __restrict__ neg,
                                             float* __restrict__ negsum){
  __shared__ __align__(16) float at[64*64];
  __shared__ __align__(16) float bt[64*64];
  const int t  = threadIdx.x;
  const int ty = t >> 4, tx = t & 15;
  const int i0 = blockIdx.y*64, j0 = blockIdx.x*64;
  const int r  = t & 63, kq = t >> 6;
  float acc[4][4] = {};
  for (int kc=0;kc<4;kc++){
    int k0 = kc*64;
    float4 av[4], bv[4];
#pragma unroll
    for (int j=0;j<4;j++){
      int kb = kq*16 + j*4;
      av[j] = *reinterpret_cast<const float4*>(hn + (size_t)(i0+r)*HID + k0 + kb);
      bv[j] = *reinterpret_cast<const float4*>(hn + (size_t)(j0+r)*HID + k0 + kb);
    }
    __syncthreads();
#pragma unroll
    for (int j=0;j<4;j++){
      int kb = kq*16 + j*4;
      at[(kb+0)*64+r]=av[j].x; at[(kb+1)*64+r]=av[j].y; at[(kb+2)*64+r]=av[j].z; at[(kb+3)*64+r]=av[j].w;
      bt[(kb+0)*64+r]=bv[j].x; bt[(kb+1)*64+r]=bv[j].y; bt[(kb+2)*64+r]=bv[j].z; bt[(kb+3)*64+r]=bv[j].w;
    }
    __syncthreads();
#pragma unroll 8
    for (int k=0;k<64;k++){
      float4 a = *reinterpret_cast<const float4*>(&at[k*64 + ty*4]);
      float4 b = *reinterpret_cast<const float4*>(&bt[k*64 + tx*4]);
      float aa[4] = {a.x,a.y,a.z,a.w}, bb[4] = {b.x,b.y,b.z,b.w};
#pragma unroll
      for (int ii=0;ii<4;ii++)
#pragma unroll
        for (int jj=0;jj<4;jj++) acc[ii][jj] = fmaf(aa[ii], bb[jj], acc[ii][jj]);
    }
  }
#pragma unroll
  for (int ii=0;ii<4;ii++){
    float4 e;
    e.x = __expf(acc[ii][0]*2.0f);
    e.y = __expf(acc[ii][1]*2.0f);
    e.z = __expf(acc[ii][2]*2.0f);
    e.w = __expf(acc[ii][3]*2.0f);
    int row = i0 + ty*4 + ii;
    *reinterpret_cast<float4*>(neg + (size_t)row*M_CL + j0 + tx*4) = e;
    float rs = e.x+e.y+e.z+e.w;
#pragma unroll
    for (int off=8;off;off>>=1) rs += __shfl_xor(rs, off, 16);
    if (tx == 0) atomicAdd(&negsum[row], rs);
  }
}

// ---------------- loss ----------------
__global__ __launch_bounds__(256) void k_loss(const float* __restrict__ neg, const float* __restrict__ negsum,
                                              const float* __restrict__ posacc, const int* __restrict__ start,
                                              const int* __restrict__ scol, const float* __restrict__ sval,
                                              double* __restrict__ loss){
  const int i = blockIdx.x, t = threadIdx.x;
  float ps[8] = {};
  const int s0 = start[i], s1 = start[i+1];
  for (int e=s0;e<s1;e++){
    int c = scol[e];
    float v = sval[e];
    const float* row = neg + (size_t)c*M_CL + t;
#pragma unroll
    for (int jj=0;jj<8;jj++) ps[jj] = fmaf(v, row[jj*256], ps[jj]);
  }
  float pos = __expf(posacc[i]);
  float part = 0.f;
#pragma unroll
  for (int jj=0;jj<8;jj++){
    int j = t + jj*256;
    part += __logf(pos + negsum[j]) - __logf(pos + ps[jj]);  // LAMDA = 1
  }
#pragma unroll
  for (int off=32;off;off>>=1) part += __shfl_xor(part, off, 64);
  __shared__ float wsum[4];
  if ((t&63) == 0) wsum[t>>6] = part;
  __syncthreads();
  if (t == 0){
    double s = (double)wsum[0] + (double)wsum[1] + (double)wsum[2] + (double)wsum[3];
    atomicAdd(loss, s);
  }
}

__global__ void k_finalize(const double* __restrict__ loss, float* __restrict__ out){
  if (threadIdx.x == 0 && blockIdx.x == 0)
    out[0] = (float)(loss[0] / ((double)M_CL * (double)M_CL));
}

// ---------------- launch ----------------
extern "C" void kernel_launch(void* const* d_in, const int* in_sizes, int n_in,
                              void* d_out, int out_size, void* d_ws, size_t ws_size,
                              hipStream_t stream){
  const float* x    = (const float*)d_in[0];
  const float* We0  = (const float*)d_in[1];
  const float* be0  = (const float*)d_in[2];
  const float* We1  = (const float*)d_in[3];
  const float* be1  = (const float*)d_in[4];
  const float* Wt0  = (const float*)d_in[5];
  const float* bt0  = (const float*)d_in[6];
  const float* Wt1  = (const float*)d_in[7];
  const float* bt1  = (const float*)d_in[8];
  const float* Wp0  = (const float*)d_in[9];
  const float* bp0  = (const float*)d_in[10];
  const float* Wp1  = (const float*)d_in[11];
  const float* bp1  = (const float*)d_in[12];
  const float* pv   = (const float*)d_in[13];
  const float* cgv  = (const float*)d_in[14];
  const int*   pas  = (const int*)d_in[15];
  const int*   cgr  = (const int*)d_in[16];
  const int*   cgc  = (const int*)d_in[17];

  char* ws = (char*)d_ws;
  float*  posacc  = (float*)(ws + OFF_POSACC);
  float*  negsum  = (float*)(ws + OFF_NEGSUM);
  int*    hist_p  = (int*)  (ws + OFF_HISTP);
  int*    cur_p   = (int*)  (ws + OFF_CURP);
  int*    hist_e  = (int*)  (ws + OFF_HISTE);
  int*    cur_e   = (int*)  (ws + OFF_CURE);
  double* lossd   = (double*)(ws + OFF_LOSS);
  int*    start_p = (int*)  (ws + OFF_STARTP);
  int*    start_e = (int*)  (ws + OFF_STARTE);
  int*    sortpt  = (int*)  (ws + OFF_SORTPT);
  int*    scol    = (int*)  (ws + OFF_SCOL);
  float*  sval    = (float*)(ws + OFF_SVAL);
  float*  cnt     = (float*)(ws + OFF_CNT);
  float*  Xc      = (float*)(ws + OFF_XC);
  float*  hc      = (float*)(ws + OFF_HC);
  float*  t0      = (float*)(ws + OFF_T0);
  float*  qb      = (float*)(ws + OFF_Q);
  float*  hn      = (float*)(ws + OFF_HN);
  float*  negbuf  = (float*)(ws + OFF_NEG);
  u16*    Wt0t    = (u16*)  (ws + OFF_WT0T);
  u16*    Wt1t    = (u16*)  (ws + OFF_WT1T);

  hipMemsetAsync(ws, 0, ZERO_BYTES, stream);

  k_hist<<<(N_PTS+255)/256, 256, 0, stream>>>(pas, N_PTS, hist_p);
  k_hist<<<(E_EDG+255)/256, 256, 0, stream>>>(cgr, E_EDG, hist_e);
  k_scan<<<1, 256, 0, stream>>>(hist_p, start_p);
  k_scan<<<1, 256, 0, stream>>>(hist_e, start_e);
  k_scatter_pts<<<(N_PTS+255)/256, 256, 0, stream>>>(pas, start_p, cur_p, sortpt);
  k_scatter_edges<<<(E_EDG+255)/256, 256, 0, stream>>>(cgr, cgc, cgv, start_e, cur_e, scol, sval);

  k_transpose_bf16<IN_DIM><<<IN_DIM, 256, 0, stream>>>(Wt0, Wt0t);   // 256*512 elems
  k_transpose_bf16<HID  ><<<HID,    256, 0, stream>>>(Wt1, Wt1t);    // 256*256 elems

  k_cluster_agg<<<M_CL, 256, 0, stream>>>(x, pv, sortpt, start_p, Xc, cnt);

  k_gemm_small<512,false,true ><<<M_CL/4, 256, 0, stream>>>(Xc, We0, be0, cnt, t0);     // hc_pre
  k_gemm_small<256,false,true ><<<M_CL/4, 256, 0, stream>>>(t0, We1, be1, cnt, hc);     // hc
  k_gemm_small<256,true ,false><<<M_CL/4, 256, 0, stream>>>(hc, Wp0, bp0, nullptr, t0); // relu
  k_gemm_small<256,false,false><<<M_CL/4, 256, 0, stream>>>(t0, Wp1, bp1, nullptr, qb); // q_pre

  k_norm_rows<<<M_CL, 256, 0, stream>>>(qb, qb);  // q
  k_norm_rows<<<M_CL, 256, 0, stream>>>(hc, hn);  // hn

  k_target_mfma<<<(N_PTS+63)/64, 256, 0, stream>>>(x, Wt0t, bt0, Wt1t, bt1, qb, pas, pv, posacc);

  dim3 g2(M_CL/64, M_CL/64);
  k_neg<<<g2, 256, 0, stream>>>(hn, negbuf, negsum);

  k_loss<<<M_CL, 256, 0, stream>>>(negbuf, negsum, posacc, start_e, scol, sval, lossd);
  k_finalize<<<1, 64, 0, stream>>>(lossd, (float*)d_out);
}